// Round 4
// baseline (47.566 us; speedup 1.0000x reference)
//
#include <hip/hip_runtime.h>
#include <hip/hip_bf16.h>

// OnlineTripletLoss: B=8192, D=128, fp32 embeddings, int32 labels, scalar out.
// d2-space fused reductions; 32x32x16 bf16 MFMA (32 rows/wave halves LDS-read
// traffic vs 16x16); LDS-staged B (global_load_lds, pre-swizzled source),
// double-buffered; sq-deferred epilogue.

#define BB 8192
#define DD 128
#define MARGIN 0.2f
#define EPS 1e-12f

#define COLS_PER_BLOCK 512
#define ROWS_PER_BLOCK 128                 // 4 waves x 32 rows
#define STAGE_COLS 64
#define NSTAGES (COLS_PER_BLOCK / STAGE_COLS)   // 8
#define STAGE_SHORTS (STAGE_COLS * DD)          // 8192 shorts = 16 KB

typedef __attribute__((ext_vector_type(8))) short short8;
typedef __attribute__((ext_vector_type(16))) float f32x16;

__device__ inline unsigned short f2bf(float f) {
    __hip_bfloat16 h = __float2bfloat16(f);
    unsigned short u;
    __builtin_memcpy(&u, &h, 2);
    return u;
}

// ---- prep: bf16 copy + packed {sq,label} meta + init hp/mn -----------------
__global__ __launch_bounds__(256) void prep_kernel(
    const float* __restrict__ x, const int* __restrict__ lab,
    unsigned short* __restrict__ xb, float2* __restrict__ meta,
    unsigned* __restrict__ hp2, unsigned* __restrict__ mn2) {
    int t = blockIdx.x * blockDim.x + threadIdx.x;   // 0 .. 8192*32-1
    int row = t >> 5;                                 // 32 threads per row
    const float4 v = reinterpret_cast<const float4*>(x)[t];

    union { unsigned short u[4]; uint2 w; } p;
    p.u[0] = f2bf(v.x); p.u[1] = f2bf(v.y);
    p.u[2] = f2bf(v.z); p.u[3] = f2bf(v.w);
    reinterpret_cast<uint2*>(xb)[t] = p.w;

    float s = v.x * v.x + v.y * v.y + v.z * v.z + v.w * v.w;
    #pragma unroll
    for (int m = 16; m >= 1; m >>= 1) s += __shfl_xor(s, m, 64);
    if ((t & 31) == 0) meta[row] = make_float2(s, __int_as_float(lab[row]));

    if (t < BB) { hp2[t] = 0u; mn2[t] = 0x7f800000u; }  // 0, +inf
}

// ---- main ------------------------------------------------------------------
// grid (64, 16), 256 threads = 4 waves. Block = 128 rows x 512-col chunk.
// Each wave: 32 rows via mfma_f32_32x32x16_bf16, A (8 K-slices) in registers.
// B tiles of 64 cols staged into LDS (dbuf) via global_load_lds, swizzled.
__global__ __launch_bounds__(256, 3) void triplet_main(
    const unsigned short* __restrict__ xb, const float2* __restrict__ meta,
    unsigned* __restrict__ hp2, unsigned* __restrict__ mn2) {
    const int tid  = threadIdx.x;
    const int wave = tid >> 6;
    const int lane = tid & 63;
    const int l31  = lane & 31;
    const int lh1  = lane >> 5;
    const int rbase = blockIdx.x * ROWS_PER_BLOCK + wave * 32;
    const int cbase = blockIdx.y * COLS_PER_BLOCK;

    __shared__ unsigned short sb[2][STAGE_SHORTS];   // 2 x 16 KB
    __shared__ float2 smeta[COLS_PER_BLOCK];         // 4 KB

    // A fragments: 32 rows, K=128 in 8 slices (held whole kernel).
    // mfma_f32_32x32x16_bf16 A layout: row = lane&31, k = (lane>>5)*8 + i.
    short8 a[8];
    {
        const unsigned short* ar = xb + (size_t)(rbase + l31) * DD + lh1 * 8;
        #pragma unroll
        for (int s = 0; s < 8; ++s)
            a[s] = *reinterpret_cast<const short8*>(ar + s * 16);
    }

    // C/D layout: col = lane&31, row_local = (r&3) + 8*(r>>2) + 4*(lane>>5).
    int li[16]; float hp[16], mn[16];
    #pragma unroll
    for (int r = 0; r < 16; ++r) {
        const int rl = (r & 3) + 8 * (r >> 2) + 4 * lh1;
        li[r] = __float_as_int(meta[rbase + rl].y);
        hp[r] = -__builtin_inff(); mn[r] = __builtin_inff();
    }

    smeta[tid] = meta[cbase + tid];
    smeta[tid + 256] = meta[cbase + tid + 256];

    // Stage 64 cols (16 KB). LDS dest linear (wave-uniform base + lane*16);
    // global SOURCE pre-swizzled: LDS(row,b) = G(row, b ^ ((row&7)<<4)).
    auto stage = [&](int g, int buf) {
        const char* src_base = (const char*)(xb + (size_t)(cbase + g * STAGE_COLS) * DD);
        #pragma unroll
        for (int p = 0; p < 4; ++p) {
            const int o   = p * 4096 + tid * 16;            // linear byte offset
            const int row = o >> 8;
            const int byt = (o & 255) ^ ((row & 7) << 4);
            const char* src = src_base + row * 256 + byt;
            char* dst = (char*)&sb[buf][0] + p * 4096 + wave * 1024;
            __builtin_amdgcn_global_load_lds(
                (const __attribute__((address_space(1))) void*)src,
                (__attribute__((address_space(3))) void*)dst, 16, 0, 0);
        }
    };

    auto compute_group = [&](int st, int gg, int buf) {
        const char* base = (const char*)&sb[buf][0];
        const int jl = gg * 32 + l31;                       // col within stage
        short8 b[8];
        #pragma unroll
        for (int s = 0; s < 8; ++s)
            b[s] = *reinterpret_cast<const short8*>(
                base + jl * 256 + ((s * 32 + lh1 * 16) ^ ((jl & 7) << 4)));
        f32x16 acc = {};
        #pragma unroll
        for (int s = 0; s < 8; ++s)
            acc = __builtin_amdgcn_mfma_f32_32x32x16_bf16(a[s], b[s], acc, 0, 0, 0);
        const float2 mj = smeta[st * STAGE_COLS + jl];
        const float sqj = mj.x;
        const int   lj  = __float_as_int(mj.y);
        #pragma unroll
        for (int r = 0; r < 16; ++r) {
            const float d2p = fmaf(acc[r], -2.0f, sqj);     // sqj - 2*dot (sqi deferred)
            const bool eq = (li[r] == lj);
            // self-pair folds into hp: its d2' ~ -sqi -> final ~0, never wins.
            hp[r] = fmaxf(hp[r], eq ? d2p : -__builtin_inff());
            mn[r] = fminf(mn[r], eq ? __builtin_inff() : d2p);
        }
    };

    stage(0, 0);
    asm volatile("s_waitcnt vmcnt(0)" ::: "memory");
    __syncthreads();
    for (int st = 0; st < NSTAGES; ++st) {
        if (st + 1 < NSTAGES) stage(st + 1, (st + 1) & 1);
        compute_group(st, 0, st & 1);
        compute_group(st, 1, st & 1);
        asm volatile("s_waitcnt vmcnt(0)" ::: "memory");
        __syncthreads();
    }

    // add deferred sqi; clamp hp to >=0 (exact: reference max(d*posmask) >= 0)
    #pragma unroll
    for (int r = 0; r < 16; ++r) {
        const int rl = (r & 3) + 8 * (r >> 2) + 4 * lh1;
        const float sqi = meta[rbase + rl].x;
        hp[r] = fmaxf(sqi + hp[r], 0.0f);
        mn[r] = sqi + mn[r];                 // +inf stays +inf
    }
    // reduce across the 32 column-lanes (xor<32 stays within each half-wave)
    #pragma unroll
    for (int m = 1; m < 32; m <<= 1) {
        #pragma unroll
        for (int r = 0; r < 16; ++r) {
            hp[r] = fmaxf(hp[r], __shfl_xor(hp[r], m, 64));
            mn[r] = fminf(mn[r], __shfl_xor(mn[r], m, 64));
        }
    }
    if (l31 == 0) {   // lanes 0 and 32 hold the two row-halves
        #pragma unroll
        for (int r = 0; r < 16; ++r) {
            const int i = rbase + (r & 3) + 8 * (r >> 2) + 4 * lh1;
            atomicMax(&hp2[i], __float_as_uint(hp[r]));  // >=0: uint order == float order
            atomicMin(&mn2[i], __float_as_uint(mn[r]));  // >=0 or +inf
        }
    }
}

// ---- finalize: per-row loss + mean -----------------------------------------
// hardest_negative = min_neq d (every row has negatives: 64 labels / 8192).
__device__ inline float d_of(float d2) {
    return (d2 > EPS) ? sqrtf(d2) : 0.0f;
}

__global__ __launch_bounds__(1024) void finalize_kernel(
    const uint4* __restrict__ hp2v, const uint4* __restrict__ mn2v,
    float* __restrict__ out) {
    float acc = 0.0f;
    #pragma unroll
    for (int it = 0; it < 2; ++it) {
        const int i = it * 1024 + threadIdx.x;     // 2048 uint4 = 8192 rows
        const uint4 h = hp2v[i];
        const uint4 m = mn2v[i];
        const unsigned hu[4] = {h.x, h.y, h.z, h.w};
        const unsigned mu[4] = {m.x, m.y, m.z, m.w};
        #pragma unroll
        for (int k = 0; k < 4; ++k) {
            const float hpv = d_of(__uint_as_float(hu[k]));
            const float mnv = d_of(__uint_as_float(mu[k]));
            acc += fmaxf(hpv - mnv + MARGIN, 0.0f);
        }
    }
    #pragma unroll
    for (int m = 1; m < 64; m <<= 1) acc += __shfl_xor(acc, m, 64);
    __shared__ float ws[16];
    const int wave = threadIdx.x >> 6;
    if ((threadIdx.x & 63) == 0) ws[wave] = acc;
    __syncthreads();
    if (threadIdx.x == 0) {
        float s = 0.0f;
        #pragma unroll
        for (int w = 0; w < 16; ++w) s += ws[w];
        out[0] = s / (float)BB;
    }
}

extern "C" void kernel_launch(void* const* d_in, const int* in_sizes, int n_in,
                              void* d_out, int out_size, void* d_ws, size_t ws_size,
                              hipStream_t stream) {
    const float* x = (const float*)d_in[0];
    const int* lab = (const int*)d_in[1];
    float* out = (float*)d_out;

    char* ws = (char*)d_ws;
    unsigned short* xb = (unsigned short*)ws;                          // 2 MB
    float2* meta = (float2*)(ws + (size_t)BB * DD * 2);                // 64 KB
    unsigned* hp2 = (unsigned*)(ws + (size_t)BB * DD * 2 + BB * 8);
    unsigned* mn2 = (unsigned*)(ws + (size_t)BB * DD * 2 + BB * 12);

    prep_kernel<<<(BB * DD / 4) / 256, 256, 0, stream>>>(x, lab, xb, meta, hp2, mn2);
    dim3 grid(BB / ROWS_PER_BLOCK, BB / COLS_PER_BLOCK);
    triplet_main<<<grid, 256, 0, stream>>>(xb, meta, hp2, mn2);
    finalize_kernel<<<1, 1024, 0, stream>>>((const uint4*)hp2, (const uint4*)mn2, out);
}